// Round 1
// baseline (55.606 us; speedup 1.0000x reference)
//
#include <hip/hip_runtime.h>
#include <hip/hip_bf16.h>

// Closed-form evaluation of the N=20 VQC:
//   psi0 is a product state with per-qubit phase pi*x[b,k].
//   CNOT ring = GF(2)-linear basis permutation L.
//     L^{-1} e_q columns: v_0={0,1}, v_q={q,q+1} (1<=q<=18), v_19={0,1,19}.
//   Observable after gate layer: O_q = RX^ RY^ Z RY RX
//     = cos(pi b)cos(pi a) Z + cos(pi b)sin(pi a) Y - sin(pi b) X
//   Diagonal contributes 0; coherence C_q = 0.5 * prod_{k in v_q} cos(pi x[b,k])
//   (parity-correction term vanishes since row_q is not a subset of v_q at n=20).
//   => out[b][q] = -sin(pi*beta_q) * prod_{k in v_q} cos(pi*x[b,k])
//   alpha and gamma drop out entirely.

#define NQ 20
#define NB 32

__global__ void vqc_closed_form(const float* __restrict__ x,
                                const float* __restrict__ params,
                                float* __restrict__ out) {
    int tid = blockIdx.x * blockDim.x + threadIdx.x;
    if (tid >= NB * NQ) return;
    int b = tid / NQ;
    int q = tid - b * NQ;

    float beta = params[NQ + q];       // params[0, n:2n]
    float sb = sinpif(beta);           // sin(pi*beta_q)

    const float* xb = x + b * NQ;
    float r;
    if (q == NQ - 1) {
        r = cospif(xb[0]) * cospif(xb[1]) * cospif(xb[NQ - 1]);
    } else if (q == 0) {
        r = cospif(xb[0]) * cospif(xb[1]);
    } else {
        r = cospif(xb[q]) * cospif(xb[q + 1]);
    }
    out[tid] = -sb * r;
}

extern "C" void kernel_launch(void* const* d_in, const int* in_sizes, int n_in,
                              void* d_out, int out_size, void* d_ws, size_t ws_size,
                              hipStream_t stream) {
    const float* x      = (const float*)d_in[0];   // (32, 20) float32
    const float* params = (const float*)d_in[1];   // (1, 60)  float32
    float* out          = (float*)d_out;           // (32, 20) float32

    const int total = NB * NQ;                      // 640
    const int block = 256;
    const int grid  = (total + block - 1) / block;  // 3
    vqc_closed_form<<<grid, block, 0, stream>>>(x, params, out);
}